// Round 4
// baseline (425.957 us; speedup 1.0000x reference)
//
#include <hip/hip_runtime.h>
#include <math.h>

#define NLV 16
#define TBL (1u << 19)
#define HMASK (TBL - 1u)
#define PRIME1 2654435761u

#define NCOARSE 6          // levels 0..5 served from LDS dense tables
#define DENSE_TOTAL 19867  // sum of (scale_l+1)^2 for l=0..5

struct Scales { float s[NLV]; };

// dense-table geometry (scale_l + 1 widths) for levels 0..5
__device__ __constant__ const int DW[NCOARSE]   = {17, 24, 34, 49, 71, 102};
__device__ __constant__ const int DOFF[NCOARSE + 1] = {0, 289, 865, 2021, 4422, 9463, 19867};

// ---- pre-kernel: materialize coarse levels as dense [y][x] arrays in ws ----
__global__ void build_dense_kernel(const float2* __restrict__ table,
                                   float2* __restrict__ dense) {
    int t = blockIdx.x * 256 + threadIdx.x;
    if (t >= DENSE_TOTAL) return;
    int l = 0;
#pragma unroll
    for (int k = 1; k < NCOARSE; ++k)
        if (t >= DOFF[k]) l = k;
    int r = t - DOFF[l];
    int w = DW[l];
    unsigned x = (unsigned)(r % w);
    unsigned y = (unsigned)(r / w);
    unsigned idx = (x ^ (y * PRIME1)) & HMASK;
    dense[t] = table[(size_t)l * TBL + idx];
}

// ---- main kernel ----
// Block = 1024 threads, stages 155 KB of dense coarse tables into LDS.
// Levels 0-5: LDS gathers (24 of 64 requests removed from global path).
// Levels 6-15: aligned-pair float4 loads (x-corner pair shares one 16 B
// load when bx even; odd lanes fetch 2 extras under exec mask) -> avg 3
// global requests/level instead of 4.
__global__ __launch_bounds__(1024) void hashgrid_mlp_kernel(
    const float2* __restrict__ pts,
    const float2* __restrict__ table,   // [16][524288] float2
    const float2* __restrict__ dense,   // ws dense coarse tables
    const float*  __restrict__ W1,      // [64][32]
    const float*  __restrict__ W2,      // [3][64]
    float* __restrict__ out,            // [N][3]
    int N, Scales sc)
{
    __shared__ float2 sd[DENSE_TOTAL];  // 158,936 B
    for (int idx = threadIdx.x; idx < DENSE_TOTAL; idx += 1024)
        sd[idx] = dense[idx];
    __syncthreads();

    int i = blockIdx.x * 1024 + threadIdx.x;
    if (i >= N) return;

    float2 p = pts[i];
    float enc[32];

    // ---- coarse levels from LDS ----
#pragma unroll
    for (int l = 0; l < NCOARSE; ++l) {
        float s  = sc.s[l];
        float px = p.x * s;              // f32 mul, bitwise == reference
        float py = p.y * s;
        float fpx = floorf(px), fpy = floorf(py);
        float fx = px - fpx, fy = py - fpy;
        int bx = (int)fpx, by = (int)fpy;
        int li = DOFF[l] + by * DW[l] + bx;
        float2 f00 = sd[li];
        float2 f01 = sd[li + DW[l]];
        float2 f10 = sd[li + 1];
        float2 f11 = sd[li + DW[l] + 1];
        float gx = 1.f - fx, gy = 1.f - fy;
        float w00 = gx * gy, w01 = gx * fy, w10 = fx * gy, w11 = fx * fy;
        enc[2*l]   = w00*f00.x + w01*f01.x + w10*f10.x + w11*f11.x;
        enc[2*l+1] = w00*f00.y + w01*f01.y + w10*f10.y + w11*f11.y;
    }

    // ---- fine levels 6..15, two groups of 5: batch-issue then interp ----
#pragma unroll
    for (int g = 0; g < 2; ++g) {
        float4 q0[5], q1[5];
        float2 e10[5], e11[5];
        unsigned par0[5], par1[5], bxo[5];
        float fxs[5], fys[5];
#pragma unroll
        for (int t = 0; t < 5; ++t) {
            int l = NCOARSE + g * 5 + t;
            float s  = sc.s[l];
            float px = p.x * s;
            float py = p.y * s;
            float fpx = floorf(px), fpy = floorf(py);
            fxs[t] = px - fpx;
            fys[t] = py - fpy;
            unsigned bx = (unsigned)(int)fpx;
            unsigned by = (unsigned)(int)fpy;
            unsigned hy0 = by * PRIME1;
            unsigned hy1 = hy0 + PRIME1;     // (by+1)*PRIME1 mod 2^32
            unsigned i0 = (bx ^ hy0) & HMASK;
            unsigned i1 = (bx ^ hy1) & HMASK;
            const float2* tl = table + (size_t)l * TBL;
            q0[t] = *(const float4*)(tl + (i0 & ~1u));   // entries {i0&~1, i0|1}
            q1[t] = *(const float4*)(tl + (i1 & ~1u));
            par0[t] = i0 & 1u;
            par1[t] = i1 & 1u;
            bxo[t]  = bx & 1u;
            e10[t] = make_float2(0.f, 0.f);
            e11[t] = make_float2(0.f, 0.f);
            if (bxo[t]) {                    // odd bx: x+1 flips >1 bit
                e10[t] = tl[((bx + 1u) ^ hy0) & HMASK];
                e11[t] = tl[((bx + 1u) ^ hy1) & HMASK];
            }
        }
        __builtin_amdgcn_sched_barrier(0);   // keep the load batch batched
#pragma unroll
        for (int t = 0; t < 5; ++t) {
            int l = NCOARSE + g * 5 + t;
            float2 f00 = par0[t] ? make_float2(q0[t].z, q0[t].w)
                                 : make_float2(q0[t].x, q0[t].y);
            float2 f01 = par1[t] ? make_float2(q1[t].z, q1[t].w)
                                 : make_float2(q1[t].x, q1[t].y);
            float2 f10 = bxo[t] ? e10[t]
                       : (par0[t] ? make_float2(q0[t].x, q0[t].y)
                                  : make_float2(q0[t].z, q0[t].w));
            float2 f11 = bxo[t] ? e11[t]
                       : (par1[t] ? make_float2(q1[t].x, q1[t].y)
                                  : make_float2(q1[t].z, q1[t].w));
            float fx = fxs[t], fy = fys[t];
            float gx = 1.f - fx, gy = 1.f - fy;
            float w00 = gx * gy, w01 = gx * fy, w10 = fx * gy, w11 = fx * fy;
            enc[2*l]   = w00*f00.x + w01*f01.x + w10*f10.x + w11*f11.x;
            enc[2*l+1] = w00*f00.y + w01*f01.y + w10*f10.y + w11*f11.y;
        }
    }

    // ---- MLP 32 -> 64 (ReLU) -> 3 ----
    float o0 = 0.f, o1 = 0.f, o2 = 0.f;
#pragma unroll
    for (int j = 0; j < 64; ++j) {
        float h = 0.f;
#pragma unroll
        for (int k = 0; k < 32; ++k)
            h = fmaf(enc[k], W1[j*32 + k], h);   // uniform addr -> s_load
        h = fmaxf(h, 0.f);
        o0 = fmaf(h, W2[      j], o0);
        o1 = fmaf(h, W2[ 64 + j], o1);
        o2 = fmaf(h, W2[128 + j], o2);
    }
    out[3*i + 0] = o0;
    out[3*i + 1] = o1;
    out[3*i + 2] = o2;
}

// ---- fallback (round-1 style) if ws is too small for the dense tables ----
__global__ __launch_bounds__(256, 4) void hashgrid_mlp_fallback(
    const float2* __restrict__ pts, const float2* __restrict__ table,
    const float* __restrict__ W1, const float* __restrict__ W2,
    float* __restrict__ out, int N, Scales sc)
{
    int i = blockIdx.x * 256 + threadIdx.x;
    if (i >= N) return;
    float2 p = pts[i];
    float enc[32];
#pragma unroll
    for (int l = 0; l < NLV; ++l) {
        float s = sc.s[l];
        float px = p.x * s, py = p.y * s;
        float fpx = floorf(px), fpy = floorf(py);
        float fx = px - fpx, fy = py - fpy;
        unsigned bx = (unsigned)(int)fpx, by = (unsigned)(int)fpy;
        unsigned hy0 = by * PRIME1, hy1 = hy0 + PRIME1;
        const float2* tl = table + (size_t)l * TBL;
        float2 f00 = tl[( bx       ^ hy0) & HMASK];
        float2 f01 = tl[( bx       ^ hy1) & HMASK];
        float2 f10 = tl[((bx + 1u) ^ hy0) & HMASK];
        float2 f11 = tl[((bx + 1u) ^ hy1) & HMASK];
        float gx = 1.f - fx, gy = 1.f - fy;
        float w00 = gx * gy, w01 = gx * fy, w10 = fx * gy, w11 = fx * fy;
        enc[2*l]   = w00*f00.x + w01*f01.x + w10*f10.x + w11*f11.x;
        enc[2*l+1] = w00*f00.y + w01*f01.y + w10*f10.y + w11*f11.y;
    }
    float o0 = 0.f, o1 = 0.f, o2 = 0.f;
#pragma unroll
    for (int j = 0; j < 64; ++j) {
        float h = 0.f;
#pragma unroll
        for (int k = 0; k < 32; ++k) h = fmaf(enc[k], W1[j*32 + k], h);
        h = fmaxf(h, 0.f);
        o0 = fmaf(h, W2[j], o0); o1 = fmaf(h, W2[64 + j], o1); o2 = fmaf(h, W2[128 + j], o2);
    }
    out[3*i] = o0; out[3*i + 1] = o1; out[3*i + 2] = o2;
}

extern "C" void kernel_launch(void* const* d_in, const int* in_sizes, int n_in,
                              void* d_out, int out_size, void* d_ws, size_t ws_size,
                              hipStream_t stream) {
    const float2* pts   = (const float2*)d_in[0];
    const float2* table = (const float2*)d_in[1];
    const float*  W1    = (const float*)d_in[2];
    const float*  W2    = (const float*)d_in[3];
    float* out = (float*)d_out;
    int N = in_sizes[0] / 2;

    // Replicate numpy: np.floor(16 * 1.447269237440378 ** arange(16)).astype(f32)
    // (level 15 is a floor boundary: 4095, NOT 4096 — host pow matches numpy).
    Scales sc;
    for (int l = 0; l < NLV; ++l)
        sc.s[l] = (float)floor(16.0 * pow(1.447269237440378, (double)l));

    if (ws_size >= DENSE_TOTAL * sizeof(float2)) {
        float2* dense = (float2*)d_ws;
        hipLaunchKernelGGL(build_dense_kernel, dim3((DENSE_TOTAL + 255) / 256),
                           dim3(256), 0, stream, table, dense);
        int blocks = (N + 1023) / 1024;
        hipLaunchKernelGGL(hashgrid_mlp_kernel, dim3(blocks), dim3(1024), 0, stream,
                           pts, table, dense, W1, W2, out, N, sc);
    } else {
        int blocks = (N + 255) / 256;
        hipLaunchKernelGGL(hashgrid_mlp_fallback, dim3(blocks), dim3(256), 0, stream,
                           pts, table, W1, W2, out, N, sc);
    }
}